// Round 1
// baseline (39455.380 us; speedup 1.0000x reference)
//
#include <hip/hip_runtime.h>
#include <cstdint>

#define TPB 256   // threads per block
#define BPB 64    // batch rows per block
#define NQ  4     // threads per batch row
#define JT  13    // hidden units per thread (4*13 = 52 >= 50)
#define HS  50    // hidden size
#define HP  52    // padded hidden (mult of 4)
#define NG  200   // 4*H gate rows
#define NGP 204   // padded gate rows
#define NK4 13    // HP/4

__device__ __forceinline__ float fsig(float x) {
  return __fdividef(1.f, 1.f + __expf(-x));
}
__device__ __forceinline__ float ftanh_(float x) {
  return 1.f - 2.f * __fdividef(1.f, 1.f + __expf(2.f * x));
}

__global__ __launch_bounds__(TPB, 1)
void lstm_fused(const float* __restrict__ x,
                const float* __restrict__ w_ih,
                const float* __restrict__ w_hh,
                const float* __restrict__ b_ih,
                const float* __restrict__ b_hh,
                const float* __restrict__ w_fc,
                const float* __restrict__ b_fc,
                float* __restrict__ out, int T)
{
  __shared__ __attribute__((aligned(16))) float w_lds[NGP * HP]; // [gate row][k]
  __shared__ __attribute__((aligned(16))) float h_lds[BPB][HP];  // [b_loc][j]
  __shared__ __attribute__((aligned(16))) float2 wb_lds[NGP];    // (w_ih, b_ih+b_hh)

  const int tid  = threadIdx.x;
  const int bloc = tid >> 2;   // 0..63
  const int q    = tid & 3;    // 0..3
  const int b    = blockIdx.x * BPB + bloc;

  // stage w_hh into LDS, zero the pads (rows>=200, cols>=50)
  for (int idx = tid; idx < NGP * HP; idx += TPB) {
    int r = idx / HP, k = idx - r * HP;
    w_lds[idx] = (r < NG && k < HS) ? w_hh[r * HS + k] : 0.f;
  }
  // h starts at zero (pads stay zero forever)
  for (int idx = tid; idx < BPB * HP; idx += TPB)
    (&h_lds[0][0])[idx] = 0.f;
  // per-gate input weight + combined bias
  for (int idx = tid; idx < NGP; idx += TPB) {
    float wi = 0.f, bs = 0.f;
    if (idx < NG) { wi = w_ih[idx]; bs = b_ih[idx] + b_hh[idx]; }
    wb_lds[idx] = make_float2(wi, bs);
  }

  float c[JT], h_loc[JT];
  #pragma unroll
  for (int i = 0; i < JT; ++i) { c[i] = 0.f; h_loc[i] = 0.f; }

  __syncthreads();

  const float* xp = x + (size_t)b * T;
  float xv = xp[0];

  #pragma unroll 1
  for (int t = 0; t < T; ++t) {
    float xnext = (t + 1 < T) ? xp[t + 1] : 0.f;  // prefetch next scalar

    // gates init: x*w_ih + (b_ih + b_hh)
    float acc[4][JT];
    #pragma unroll
    for (int s = 0; s < 4; ++s)
      #pragma unroll
      for (int i = 0; i < JT; ++i) {
        float2 wb = wb_lds[s * HS + q * JT + i];
        acc[s][i] = fmaf(xv, wb.x, wb.y);
      }

    // gates += h @ w_hh^T  (k-loop rolled: keeps body I-cache-small,
    // all register arrays statically indexed)
    #pragma unroll 1
    for (int k4 = 0; k4 < NK4; ++k4) {
      const float4 hv = *(const float4*)&h_lds[bloc][k4 * 4];
      #pragma unroll
      for (int s = 0; s < 4; ++s)
        #pragma unroll
        for (int i = 0; i < JT; ++i) {
          const float4 wv =
              *(const float4*)&w_lds[(s * HS + q * JT + i) * HP + k4 * 4];
          acc[s][i] = fmaf(wv.x, hv.x, acc[s][i]);
          acc[s][i] = fmaf(wv.y, hv.y, acc[s][i]);
          acc[s][i] = fmaf(wv.z, hv.z, acc[s][i]);
          acc[s][i] = fmaf(wv.w, hv.w, acc[s][i]);
        }
    }

    __syncthreads();  // all reads of h done before overwrite

    #pragma unroll
    for (int i = 0; i < JT; ++i) {
      float ig = fsig(acc[0][i]);
      float fg = fsig(acc[1][i]);
      float gg = ftanh_(acc[2][i]);
      float og = fsig(acc[3][i]);
      float cn = fmaf(fg, c[i], ig * gg);
      c[i] = cn;
      float hn = og * ftanh_(cn);
      h_loc[i] = hn;
      int jg = q * JT + i;
      if (jg < HS) h_lds[bloc][jg] = hn;
    }

    __syncthreads();  // new h visible to all
    xv = xnext;
  }

  // fc head on last hidden state: out[b] = h . w_fc + b_fc
  float sum = 0.f;
  #pragma unroll
  for (int i = 0; i < JT; ++i) {
    int jg = q * JT + i;
    if (jg < HS) sum = fmaf(h_loc[i], w_fc[jg], sum);
  }
  sum += __shfl_xor(sum, 1);
  sum += __shfl_xor(sum, 2);
  if (q == 0) out[b] = sum + b_fc[0];
}

extern "C" void kernel_launch(void* const* d_in, const int* in_sizes, int n_in,
                              void* d_out, int out_size, void* d_ws, size_t ws_size,
                              hipStream_t stream) {
  const float* x    = (const float*)d_in[0];
  const float* w_ih = (const float*)d_in[1];
  const float* w_hh = (const float*)d_in[2];
  const float* b_ih = (const float*)d_in[3];
  const float* b_hh = (const float*)d_in[4];
  const float* w_fc = (const float*)d_in[5];
  const float* b_fc = (const float*)d_in[6];
  float* out = (float*)d_out;

  const int B = out_size;          // 16384
  const int T = in_sizes[0] / B;   // 2048

  dim3 grid(B / BPB), block(TPB);
  hipLaunchKernelGGL(lstm_fused, grid, block, 0, stream,
                     x, w_ih, w_hh, b_ih, b_hh, w_fc, b_fc, out, T);
}

// Round 2
// 6193.777 us; speedup vs baseline: 6.3702x; 6.3702x over previous
//
#include <hip/hip_runtime.h>
#include <cstdint>

typedef __attribute__((ext_vector_type(8))) short short8;
typedef __attribute__((ext_vector_type(4))) float f32x4;

#define TPB 256
#define MB  16      // batch rows per block
#define HS  50      // hidden size
#define HSTR 72     // h_lds row stride in halves (144B: 16B-aligned, bank shift +4)
#define XSTR 68     // x_lds row stride in floats (272B: 16B-aligned, bank shift +4)

__device__ __forceinline__ unsigned short bf16_rn(float f) {
  union { float f; unsigned u; } v; v.f = f;
  unsigned r = v.u + 0x7FFFu + ((v.u >> 16) & 1u);
  return (unsigned short)(r >> 16);
}
__device__ __forceinline__ float bf16_f(unsigned short h) {
  union { unsigned u; float f; } v; v.u = ((unsigned)h) << 16;
  return v.f;
}
__device__ __forceinline__ float fsig(float x) {
  return __fdividef(1.f, 1.f + __expf(-x));
}
__device__ __forceinline__ float ftanh_(float x) {
  return 1.f - 2.f * __fdividef(1.f, 1.f + __expf(2.f * x));
}

// Gate GEMM per step: gates[16 b][256 n] = A[16 b][64 k] * B[64 k][256 n]
//   k: 0..49 = h(t-1), 50 = xv(t), 51 = 1.0, 52..63 = 0
//   n = s*64 + j (gate s, hidden col j); wave w owns j in [16w, 16w+16) for ALL s
// MFMA 16x16x32 bf16, 3 passes: Ah*Bh + Ah*Bl + Al*Bh  (~2^-17 rel err)
__global__ __launch_bounds__(TPB, 4)
void lstm_mfma(const float* __restrict__ x,
               const float* __restrict__ w_ih,
               const float* __restrict__ w_hh,
               const float* __restrict__ b_ih,
               const float* __restrict__ b_hh,
               const float* __restrict__ w_fc,
               const float* __restrict__ b_fc,
               float* __restrict__ out, int T)
{
  __shared__ unsigned short h_hi[MB][HSTR];
  __shared__ unsigned short h_lo[MB][HSTR];
  __shared__ float x_lds[2][MB][XSTR];

  const int tid  = threadIdx.x;
  const int wid  = tid >> 6;     // wave id = j-chunk owner
  const int lane = tid & 63;
  const int l15  = lane & 15;
  const int lhi  = lane >> 4;    // 0..3
  const int b0   = blockIdx.x * MB;

  // ---- build static B-fragments (w hi/lo) in registers ----
  // B-frag layout (16x16x32): lane holds col = l15, k = kf*32 + lhi*8 + i
  short8 Bh[4][2], Bl[4][2];
  const int j = wid * 16 + l15;                 // gate col this lane loads/owns
  #pragma unroll
  for (int s = 0; s < 4; ++s) {
    #pragma unroll
    for (int kf = 0; kf < 2; ++kf) {
      #pragma unroll
      for (int i = 0; i < 8; ++i) {
        int k = kf * 32 + lhi * 8 + i;
        float v = 0.f;
        if (j < HS) {
          int row = s * HS + j;
          if (k < HS)        v = w_hh[row * HS + k];
          else if (k == 50)  v = w_ih[row];
          else if (k == 51)  v = b_ih[row] + b_hh[row];
        }
        unsigned short hi = bf16_rn(v);
        float lo = v - bf16_f(hi);
        Bh[s][kf][i] = (short)hi;
        Bl[s][kf][i] = (short)bf16_rn(lo);
      }
    }
  }

  // ---- init LDS ----
  for (int idx = tid; idx < MB * HSTR; idx += TPB) {
    (&h_hi[0][0])[idx] = 0; (&h_lo[0][0])[idx] = 0;
  }
  __syncthreads();
  {
    // stage x chunk 0 (coalesced float4)
    int bb = tid >> 4, tt = (tid & 15) * 4;
    const float4 v = *(const float4*)(x + (size_t)(b0 + bb) * T + tt);
    *(float4*)&x_lds[0][bb][tt] = v;
    if (tid < MB) {
      h_hi[tid][51] = 0x3F80;  // const 1.0 (bias row); lo stays 0
      float xv = x[(size_t)(b0 + tid) * T];     // xv(0)
      unsigned short hh = bf16_rn(xv);
      h_hi[tid][50] = hh;
      h_lo[tid][50] = bf16_rn(xv - bf16_f(hh));
    }
  }
  __syncthreads();

  float c_st[4] = {0.f, 0.f, 0.f, 0.f};
  const bool jval = (j < HS);
  const int nch = T >> 6;

  for (int t = 0; t < T; ++t) {
    // stage next x chunk mid-way through current one (double-buffered)
    if ((t & 63) == 32) {
      int c1 = (t >> 6) + 1;
      if (c1 < nch) {
        int bb = tid >> 4, tt = (tid & 15) * 4;
        const float4 v = *(const float4*)(x + (size_t)(b0 + bb) * T + c1 * 64 + tt);
        *(float4*)&x_lds[c1 & 1][bb][tt] = v;
      }
    }

    // A-frags: lane = row b = l15, k = kf*32 + lhi*8 + {0..7}
    const int ak = lhi * 8;
    short8 Ah0 = *(const short8*)&h_hi[l15][ak];
    short8 Al0 = *(const short8*)&h_lo[l15][ak];
    short8 Ah1 = *(const short8*)&h_hi[l15][ak + 32];
    short8 Al1 = *(const short8*)&h_lo[l15][ak + 32];

    __syncthreads();   // all A-reads done before anyone overwrites h

    f32x4 acc[4];
    #pragma unroll
    for (int s = 0; s < 4; ++s) acc[s] = (f32x4){0.f, 0.f, 0.f, 0.f};
    #pragma unroll
    for (int s = 0; s < 4; ++s) {
      acc[s] = __builtin_amdgcn_mfma_f32_16x16x32_bf16(Ah0, Bh[s][0], acc[s], 0, 0, 0);
      acc[s] = __builtin_amdgcn_mfma_f32_16x16x32_bf16(Ah0, Bl[s][0], acc[s], 0, 0, 0);
      acc[s] = __builtin_amdgcn_mfma_f32_16x16x32_bf16(Al0, Bh[s][0], acc[s], 0, 0, 0);
      acc[s] = __builtin_amdgcn_mfma_f32_16x16x32_bf16(Ah1, Bh[s][1], acc[s], 0, 0, 0);
      acc[s] = __builtin_amdgcn_mfma_f32_16x16x32_bf16(Ah1, Bl[s][1], acc[s], 0, 0, 0);
      acc[s] = __builtin_amdgcn_mfma_f32_16x16x32_bf16(Al1, Bh[s][1], acc[s], 0, 0, 0);
    }

    // elementwise update: lane owns (b = lhi*4 + r, j) for r = 0..3
    #pragma unroll
    for (int r = 0; r < 4; ++r) {
      float si = fsig(acc[0][r]);
      float sf = fsig(acc[1][r]);
      float tg = ftanh_(acc[2][r]);
      float so = fsig(acc[3][r]);
      float cn = fmaf(sf, c_st[r], si * tg);
      c_st[r] = cn;
      float hn = so * ftanh_(cn);
      if (jval) {
        int br = lhi * 4 + r;
        unsigned short hh = bf16_rn(hn);
        h_hi[br][j] = hh;
        h_lo[br][j] = bf16_rn(hn - bf16_f(hh));
      }
    }

    // write xv(t+1) into k-col 50 (wave 0, one lane per batch row)
    if (tid < MB && t + 1 < T) {
      int t1 = t + 1;
      float xv = x_lds[(t1 >> 6) & 1][tid][t1 & 63];
      unsigned short hh = bf16_rn(xv);
      h_hi[tid][50] = hh;
      h_lo[tid][50] = bf16_rn(xv - bf16_f(hh));
    }

    __syncthreads();   // h(t), xv(t+1) visible to all
  }

  // fc head on final h
  if (tid < MB) {
    float s = 0.f;
    for (int jj = 0; jj < HS; ++jj) {
      float hv = bf16_f(h_hi[tid][jj]) + bf16_f(h_lo[tid][jj]);
      s = fmaf(hv, w_fc[jj], s);
    }
    out[b0 + tid] = s + b_fc[0];
  }
}

extern "C" void kernel_launch(void* const* d_in, const int* in_sizes, int n_in,
                              void* d_out, int out_size, void* d_ws, size_t ws_size,
                              hipStream_t stream) {
  const float* x    = (const float*)d_in[0];
  const float* w_ih = (const float*)d_in[1];
  const float* w_hh = (const float*)d_in[2];
  const float* b_ih = (const float*)d_in[3];
  const float* b_hh = (const float*)d_in[4];
  const float* w_fc = (const float*)d_in[5];
  const float* b_fc = (const float*)d_in[6];
  float* out = (float*)d_out;

  const int B = out_size;          // 16384
  const int T = in_sizes[0] / B;   // 2048

  dim3 grid(B / MB), block(TPB);
  hipLaunchKernelGGL(lstm_mfma, grid, block, 0, stream,
                     x, w_ih, w_hh, b_ih, b_hh, w_fc, b_fc, out, T);
}

// Round 3
// 2624.247 us; speedup vs baseline: 15.0349x; 2.3602x over previous
//
#include <hip/hip_runtime.h>
#include <cstdint>

typedef __attribute__((ext_vector_type(8))) short short8;
typedef __attribute__((ext_vector_type(4))) float f32x4;
typedef __attribute__((ext_vector_type(2))) float f32x2;

#define TPB  256
#define MB   16      // batch rows per block
#define HS   50      // hidden size
#define HSTR 72      // h row stride in halves (144B, 16B-aligned)
#define XSTR 68      // x row stride in floats (272B, 16B-aligned)
#define L2E  1.4426950408889634f
#define L2E2 2.8853900817779268f

__device__ __forceinline__ float ex2(float x) {
#if __has_builtin(__builtin_amdgcn_exp2f)
  return __builtin_amdgcn_exp2f(x);
#else
  float r; asm("v_exp_f32 %0, %1" : "=v"(r) : "v"(x)); return r;
#endif
}
__device__ __forceinline__ float rcp_(float x) {
#if __has_builtin(__builtin_amdgcn_rcpf)
  return __builtin_amdgcn_rcpf(x);
#else
  float r; asm("v_rcp_f32 %0, %1" : "=v"(r) : "v"(x)); return r;
#endif
}
__device__ __forceinline__ unsigned short bf16_rne(float f) {
  unsigned r;
  asm("v_cvt_pk_bf16_f32 %0, %1, %2" : "=v"(r) : "v"(f), "v"(f));
  return (unsigned short)r;
}
__device__ __forceinline__ float bf16f(unsigned short h) {
  union { unsigned u; float f; } v; v.u = ((unsigned)h) << 16; return v.f;
}
// column swizzle: XOR the 8-col block index with (row>>2)&3 — spreads the
// 4 rows a wave writes per ds_write across all 32 banks; identical helper
// used on every read and write so it is self-consistent.
__device__ __forceinline__ int swcol(int row, int col) {
  return (((col >> 3) ^ ((row >> 2) & 3)) << 3) | (col & 7);
}

// K layout (A-matrix, 64 cols): 0..49 = h(t-1) bf16, 50 = xv_hi, 51 = xv_lo,
// 52 = 1.0 (bias row), 53..63 = 0.  B rows prescaled by log2e (2*log2e for g)
// so all activations are bare exp2.
__global__ __launch_bounds__(TPB, 4)
void lstm_mfma3(const float* __restrict__ x,
                const float* __restrict__ w_ih,
                const float* __restrict__ w_hh,
                const float* __restrict__ b_ih,
                const float* __restrict__ b_hh,
                const float* __restrict__ w_fc,
                const float* __restrict__ b_fc,
                float* __restrict__ out, int T)
{
  __shared__ __attribute__((aligned(16))) unsigned short hbuf[2][MB][HSTR];
  __shared__ __attribute__((aligned(16))) float x_lds[2][MB][XSTR];

  const int tid  = threadIdx.x;
  const int wid  = tid >> 6;
  const int lane = tid & 63;
  const int l15  = lane & 15;
  const int lhi  = lane >> 4;      // 0..3
  const int b0   = blockIdx.x * MB;
  const int j    = wid * 16 + l15; // gate column this lane owns
  const bool jval = (j < HS);

  // ---- build static B-fragments (w hi/lo, prescaled) ----
  short8 Bh[4][2], Bl[4][2];
  #pragma unroll
  for (int s = 0; s < 4; ++s) {
    const float sc = (s == 2) ? L2E2 : L2E;
    #pragma unroll
    for (int kf = 0; kf < 2; ++kf) {
      #pragma unroll
      for (int i = 0; i < 8; ++i) {
        int k = kf * 32 + lhi * 8 + i;
        float val = 0.f;
        if (jval) {
          int row = s * HS + j;
          if (k < HS)                    val = w_hh[row * HS + k] * sc;
          else if (k == 50 || k == 51)   val = w_ih[row] * sc;
          else if (k == 52)              val = (b_ih[row] + b_hh[row]) * sc;
        }
        unsigned short hi = bf16_rne(val);
        float lo = val - bf16f(hi);
        Bh[s][kf][i] = (short)hi;
        Bl[s][kf][i] = (short)bf16_rne(lo);
      }
    }
  }

  // ---- init LDS ----
  for (int idx = tid; idx < 2 * MB * HSTR; idx += TPB)
    (&hbuf[0][0][0])[idx] = 0;
  __syncthreads();
  {
    int bb = tid >> 4, tt = (tid & 15) * 4;
    *(float4*)&x_lds[0][bb][tt] =
        *(const float4*)(x + (size_t)(b0 + bb) * T + tt);
    if (tid < MB) {
      // bias-1.0 col in BOTH buffers; xv(0) hi/lo in buf 0
      hbuf[0][tid][swcol(tid, 52)] = 0x3F80;
      hbuf[1][tid][swcol(tid, 52)] = 0x3F80;
      float xv = x[(size_t)(b0 + tid) * T];
      unsigned short hh = bf16_rne(xv);
      hbuf[0][tid][swcol(tid, 50)] = hh;
      hbuf[0][tid][swcol(tid, 51)] = bf16_rne(xv - bf16f(hh));
    }
  }
  __syncthreads();

  // loop-invariant addresses (halves)
  const int keyr  = (l15 >> 2) & 3;
  const int offA0 = l15 * HSTR + (((lhi ^ keyr) << 3));
  const int offA1 = l15 * HSTR + ((((lhi + 4) ^ keyr) << 3));
  const int offW0 = (lhi * 4) * HSTR + swcol(lhi * 4, j);  // +r*HSTR, key==lhi for all 4 rows
  const int offX  = (tid < MB) ? (tid * HSTR + ((6 ^ ((tid >> 2) & 3)) << 3)) : 0;

  f32x2 cA = {0.f, 0.f}, cB = {0.f, 0.f};

  const unsigned short* hr = &hbuf[0][0][0];
  unsigned short*       hw = &hbuf[1][0][0];
  const int nch = T >> 6;

  for (int t = 0; t < T; ++t) {
    // stage next 64-step x chunk mid-way through the current one
    if ((t & 63) == 32) {
      int c1 = (t >> 6) + 1;
      if (c1 < nch) {
        int bb = tid >> 4, tt = (tid & 15) * 4;
        *(float4*)&x_lds[c1 & 1][bb][tt] =
            *(const float4*)(x + (size_t)(b0 + bb) * T + c1 * 64 + tt);
      }
    }

    const short8 Ah0 = *(const short8*)(hr + offA0);
    const short8 Ah1 = *(const short8*)(hr + offA1);

    f32x4 acc[4];
    #pragma unroll
    for (int s = 0; s < 4; ++s) {
      acc[s] = __builtin_amdgcn_mfma_f32_16x16x32_bf16(Ah0, Bh[s][0],
                   (f32x4){0.f, 0.f, 0.f, 0.f}, 0, 0, 0);
      acc[s] = __builtin_amdgcn_mfma_f32_16x16x32_bf16(Ah0, Bl[s][0], acc[s], 0, 0, 0);
      acc[s] = __builtin_amdgcn_mfma_f32_16x16x32_bf16(Ah1, Bh[s][1], acc[s], 0, 0, 0);
      acc[s] = __builtin_amdgcn_mfma_f32_16x16x32_bf16(Ah1, Bl[s][1], acc[s], 0, 0, 0);
    }

    // elementwise (r-pairs; ops vectorize to v_pk_*):
    //   u=e^-ai v=e^2ag w=e^-af z=e^-ao ; ig=(v-1)/((1+u)(1+v))
    //   c'=c*rcp(1+w)+ig (clamp +-30) ; q=e^2c' ; h=(q-1)/((1+z)(1+q))
    f32x2 h2[2];
    #pragma unroll
    for (int P = 0; P < 2; ++P) {
      f32x2& c2 = P ? cB : cA;
      f32x2 u, v, w, z, q, ruv, rw, rzq;
      u[0] = ex2(-acc[0][2*P]);  u[1] = ex2(-acc[0][2*P+1]);
      v[0] = ex2( acc[2][2*P]);  v[1] = ex2( acc[2][2*P+1]);
      w[0] = ex2(-acc[1][2*P]);  w[1] = ex2(-acc[1][2*P+1]);
      z[0] = ex2(-acc[3][2*P]);  z[1] = ex2(-acc[3][2*P+1]);
      f32x2 t1 = (u + 1.f) * (v + 1.f);
      ruv[0] = rcp_(t1[0]); ruv[1] = rcp_(t1[1]);
      f32x2 ig = (v - 1.f) * ruv;
      f32x2 t2 = w + 1.f;
      rw[0] = rcp_(t2[0]); rw[1] = rcp_(t2[1]);
      f32x2 cn = c2 * rw + ig;
      cn[0] = fminf(fmaxf(cn[0], -30.f), 30.f);
      cn[1] = fminf(fmaxf(cn[1], -30.f), 30.f);
      c2 = cn;
      f32x2 tq = cn * L2E2;
      q[0] = ex2(tq[0]); q[1] = ex2(tq[1]);
      f32x2 t3 = (z + 1.f) * (q + 1.f);
      rzq[0] = rcp_(t3[0]); rzq[1] = rcp_(t3[1]);
      h2[P] = (q - 1.f) * rzq;
    }

    if (jval) {
      hw[offW0           ] = bf16_rne(h2[0][0]);
      hw[offW0 +     HSTR] = bf16_rne(h2[0][1]);
      hw[offW0 + 2 * HSTR] = bf16_rne(h2[1][0]);
      hw[offW0 + 3 * HSTR] = bf16_rne(h2[1][1]);
    }

    // xv(t+1) hi/lo into the buffer the next step reads (cols 50,51 share a dword)
    if (tid < MB && t + 1 < T) {
      int t1i = t + 1;
      float xv = x_lds[(t1i >> 6) & 1][tid][t1i & 63];
      unsigned short hh = bf16_rne(xv);
      unsigned short hl = bf16_rne(xv - bf16f(hh));
      *(unsigned*)(hw + offX + 2) = (unsigned)hh | ((unsigned)hl << 16);
    }

    __syncthreads();   // writes to hw visible; everyone done reading hr

    unsigned short* tmp = (unsigned short*)hr; hr = hw; hw = tmp;
  }

  // fc head on final h (in hbuf[T&1] == hr after the last swap)
  if (tid < MB) {
    const unsigned short* hfin = hr + tid * HSTR;
    float s = 0.f;
    for (int jj = 0; jj < HS; ++jj)
      s = fmaf(bf16f(hfin[swcol(tid, jj)]), w_fc[jj], s);
    out[b0 + tid] = s + b_fc[0];
  }
}

extern "C" void kernel_launch(void* const* d_in, const int* in_sizes, int n_in,
                              void* d_out, int out_size, void* d_ws, size_t ws_size,
                              hipStream_t stream) {
  const float* x    = (const float*)d_in[0];
  const float* w_ih = (const float*)d_in[1];
  const float* w_hh = (const float*)d_in[2];
  const float* b_ih = (const float*)d_in[3];
  const float* b_hh = (const float*)d_in[4];
  const float* w_fc = (const float*)d_in[5];
  const float* b_fc = (const float*)d_in[6];
  float* out = (float*)d_out;

  const int B = out_size;          // 16384
  const int T = in_sizes[0] / B;   // 2048

  dim3 grid(B / MB), block(TPB);
  hipLaunchKernelGGL(lstm_mfma3, grid, block, 0, stream,
                     x, w_ih, w_hh, b_ih, b_hh, w_fc, b_fc, out, T);
}

// Round 4
// 2314.609 us; speedup vs baseline: 17.0462x; 1.1338x over previous
//
#include <hip/hip_runtime.h>
#include <cstdint>

typedef __attribute__((ext_vector_type(8))) short short8;
typedef __attribute__((ext_vector_type(4))) float f32x4;
typedef __attribute__((ext_vector_type(2))) float f32x2;

#define TPB  256
#define MB   16      // batch rows per block
#define HS   50      // hidden size
#define HSTR 72      // h row stride in halves (144B, 16B-aligned)
#define XSTR 68      // x row stride in u32 (272B, 16B-aligned)
#define L2E  1.4426950408889634f
#define L2E2 2.8853900817779268f

__device__ __forceinline__ float ex2(float x) {
#if __has_builtin(__builtin_amdgcn_exp2f)
  return __builtin_amdgcn_exp2f(x);
#else
  float r; asm("v_exp_f32 %0, %1" : "=v"(r) : "v"(x)); return r;
#endif
}
__device__ __forceinline__ float rcp_(float x) {
#if __has_builtin(__builtin_amdgcn_rcpf)
  return __builtin_amdgcn_rcpf(x);
#else
  float r; asm("v_rcp_f32 %0, %1" : "=v"(r) : "v"(x)); return r;
#endif
}
__device__ __forceinline__ unsigned short bf16_rne(float f) {
  unsigned r;
  asm("v_cvt_pk_bf16_f32 %0, %1, %2" : "=v"(r) : "v"(f), "v"(f));
  return (unsigned short)r;
}
__device__ __forceinline__ float bf16f(unsigned short h) {
  union { unsigned u; float f; } v; v.u = ((unsigned)h) << 16; return v.f;
}
// pack x value as (hi bf16 | lo bf16 << 16)
__device__ __forceinline__ unsigned packx(float f) {
  unsigned short hi = bf16_rne(f);
  unsigned short lo = bf16_rne(f - bf16f(hi));
  return (unsigned)hi | ((unsigned)lo << 16);
}
// column swizzle: XOR 8-col block index with (row>>2)&3 (consistent read/write)
__device__ __forceinline__ int swcol(int row, int col) {
  return (((col >> 3) ^ ((row >> 2) & 3)) << 3) | (col & 7);
}

// A (per step): 16 rows (batch) x 64 K-cols:
//   k 0..49 = h(t-1) bf16, k50 = xv_hi, k51 = xv_lo, k52 = xv_hi,
//   k53 = 1.0, k54 = 1.0, k55..63 = 0
// B rows prescaled by log2e (2*log2e for g). B frag1 k-slots:
//   k50,k51 = w_ih_hi, k52 = w_ih_lo, k53 = bias_hi, k54 = bias_lo
// MFMA per gate: Ah0*Bh0 + Ah0*Bl0 + Ah1*Bh1   (12 total)
__global__ __launch_bounds__(TPB, 4)
void lstm_mfma4(const float* __restrict__ x,
                const float* __restrict__ w_ih,
                const float* __restrict__ w_hh,
                const float* __restrict__ b_ih,
                const float* __restrict__ b_hh,
                const float* __restrict__ w_fc,
                const float* __restrict__ b_fc,
                float* __restrict__ out, int T)
{
  __shared__ __attribute__((aligned(16))) unsigned short hbuf[2][MB][HSTR];
  __shared__ __attribute__((aligned(16))) unsigned x_lds[2][MB][XSTR];

  const int tid  = threadIdx.x;
  const int wid  = tid >> 6;
  const int lane = tid & 63;
  const int l15  = lane & 15;
  const int lhi  = lane >> 4;      // 0..3
  const int b0   = blockIdx.x * MB;
  const int j    = wid * 16 + l15; // gate column this lane owns
  const bool jval = (j < HS);
  const bool inj  = (lhi == 2);    // lanes whose Ah1 carries k=48..55

  // ---- build static B-fragments ----
  short8 Bh[4][2], Bl0[4];
  #pragma unroll
  for (int s = 0; s < 4; ++s) {
    const float sc = (s == 2) ? L2E2 : L2E;
    float wsc = 0.f, bsc = 0.f;
    if (jval) {
      int row = s * HS + j;
      wsc = w_ih[row] * sc;
      bsc = (b_ih[row] + b_hh[row]) * sc;
    }
    const unsigned short wh = bf16_rne(wsc);
    const unsigned short wl = bf16_rne(wsc - bf16f(wh));
    const unsigned short bh = bf16_rne(bsc);
    const unsigned short bl = bf16_rne(bsc - bf16f(bh));
    #pragma unroll
    for (int i = 0; i < 8; ++i) {           // frag 0: k = 0..31, hi+lo
      int k = lhi * 8 + i;
      float val = jval ? w_hh[(s * HS + j) * HS + k] * sc : 0.f;
      unsigned short hi = bf16_rne(val);
      Bh[s][0][i] = (short)hi;
      Bl0[s][i]   = (short)bf16_rne(val - bf16f(hi));
    }
    #pragma unroll
    for (int i = 0; i < 8; ++i) {           // frag 1: k = 32..63, hi only
      int k = 32 + lhi * 8 + i;
      unsigned short hv = 0;
      if (jval) {
        if (k < HS)                hv = bf16_rne(w_hh[(s * HS + j) * HS + k] * sc);
        else if (k == 50 || k == 51) hv = wh;
        else if (k == 52)          hv = wl;
        else if (k == 53)          hv = bh;
        else if (k == 54)          hv = bl;
      }
      Bh[s][1][i] = (short)hv;
    }
  }

  // ---- init LDS ----
  for (int idx = tid; idx < 2 * MB * HSTR; idx += TPB)
    (&hbuf[0][0][0])[idx] = 0;
  {
    // stage x chunk 0 (coalesced float4 -> packed hi/lo u32)
    int bb = tid >> 4, tt = (tid & 15) * 4;
    const f32x4 v = *(const f32x4*)(x + (size_t)(b0 + bb) * T + tt);
    uint4 up;
    up.x = packx(v[0]); up.y = packx(v[1]); up.z = packx(v[2]); up.w = packx(v[3]);
    *(uint4*)&x_lds[0][bb][tt] = up;
  }
  __syncthreads();

  // loop-invariant LDS offsets (halves)
  const int keyr  = (l15 >> 2) & 3;
  const int offA0 = l15 * HSTR + ((lhi ^ keyr) << 3);
  const int offA1 = l15 * HSTR + (((lhi + 4) ^ keyr) << 3);
  const int offW0 = (lhi * 4) * HSTR + swcol(lhi * 4, j);

  f32x2 cA = {0.f, 0.f}, cB = {0.f, 0.f};
  f32x4 xf = {0.f, 0.f, 0.f, 0.f};

  const unsigned short* hr = &hbuf[0][0][0];
  unsigned short*       hw = &hbuf[1][0][0];
  const int nch = T >> 6;

  for (int t = 0; t < T; ++t) {
    // T14-split x staging: issue global load early, LDS-write late
    if ((t & 63) == 16) {
      int c1 = (t >> 6) + 1;
      if (c1 < nch)
        xf = *(const f32x4*)(x + (size_t)(b0 + (tid >> 4)) * T + c1 * 64 + (tid & 15) * 4);
    }
    if ((t & 63) == 44) {
      int c1 = (t >> 6) + 1;
      if (c1 < nch) {
        uint4 up;
        up.x = packx(xf[0]); up.y = packx(xf[1]);
        up.z = packx(xf[2]); up.w = packx(xf[3]);
        *(uint4*)&x_lds[c1 & 1][tid >> 4][(tid & 15) * 4] = up;
      }
    }

    // A-frags + xv/bias register injection (lanes lhi==2 only)
    const unsigned xp = x_lds[(t >> 6) & 1][l15][t & 63];
    const short8 A0 = *(const short8*)(hr + offA0);
    union { short8 s8; unsigned u[4]; } a1;
    a1.s8 = *(const short8*)(hr + offA1);
    a1.u[1] = inj ? xp : a1.u[1];
    a1.u[2] = inj ? ((xp & 0xFFFFu) | 0x3F800000u) : a1.u[2];
    a1.u[3] = inj ? 0x00003F80u : a1.u[3];

    f32x4 acc[4];
    #pragma unroll
    for (int s = 0; s < 4; ++s) {
      acc[s] = __builtin_amdgcn_mfma_f32_16x16x32_bf16(A0, Bh[s][0],
                   (f32x4){0.f, 0.f, 0.f, 0.f}, 0, 0, 0);
      acc[s] = __builtin_amdgcn_mfma_f32_16x16x32_bf16(A0, Bl0[s], acc[s], 0, 0, 0);
      acc[s] = __builtin_amdgcn_mfma_f32_16x16x32_bf16(a1.s8, Bh[s][1], acc[s], 0, 0, 0);
    }

    // elementwise: u=2^-ai v=2^2ag w=2^-af z=2^-ao
    //   c' = (c*t1 + (v-1)*wp) / (t1*wp),  t1=(1+u)(1+v), wp=1+w   [1 rcp]
    //   q = 2^(2c') ; h = (q-1)/((1+z)(1+q))                        [1 rcp]
    f32x2 h2[2];
    #pragma unroll
    for (int P = 0; P < 2; ++P) {
      f32x2& c2 = P ? cB : cA;
      f32x2 u, v, w, z, q, rD, r3;
      u[0] = ex2(-acc[0][2*P]);  u[1] = ex2(-acc[0][2*P+1]);
      v[0] = ex2( acc[2][2*P]);  v[1] = ex2( acc[2][2*P+1]);
      w[0] = ex2(-acc[1][2*P]);  w[1] = ex2(-acc[1][2*P+1]);
      z[0] = ex2(-acc[3][2*P]);  z[1] = ex2(-acc[3][2*P+1]);
      f32x2 t1 = (u + 1.f) * (v + 1.f);
      f32x2 wp = w + 1.f;
      f32x2 D  = t1 * wp;
      rD[0] = rcp_(D[0]); rD[1] = rcp_(D[1]);
      f32x2 num = c2 * t1 + (v - 1.f) * wp;
      f32x2 cn = num * rD;
      cn[0] = fminf(fmaxf(cn[0], -30.f), 30.f);
      cn[1] = fminf(fmaxf(cn[1], -30.f), 30.f);
      c2 = cn;
      q[0] = ex2(cn[0] * L2E2); q[1] = ex2(cn[1] * L2E2);
      f32x2 t3 = (z + 1.f) * (q + 1.f);
      r3[0] = rcp_(t3[0]); r3[1] = rcp_(t3[1]);
      h2[P] = (q - 1.f) * r3;
    }

    if (jval) {
      hw[offW0           ] = bf16_rne(h2[0][0]);
      hw[offW0 +     HSTR] = bf16_rne(h2[0][1]);
      hw[offW0 + 2 * HSTR] = bf16_rne(h2[1][0]);
      hw[offW0 + 3 * HSTR] = bf16_rne(h2[1][1]);
    }

    __syncthreads();   // h(t) visible; everyone done reading hr

    unsigned short* tmp = (unsigned short*)hr; hr = hw; hw = tmp;
  }

  // fc head on final h
  if (tid < MB) {
    const unsigned short* hfin = hr + tid * HSTR;
    float s = 0.f;
    for (int jj = 0; jj < HS; ++jj)
      s = fmaf(bf16f(hfin[swcol(tid, jj)]), w_fc[jj], s);
    out[b0 + tid] = s + b_fc[0];
  }
}

extern "C" void kernel_launch(void* const* d_in, const int* in_sizes, int n_in,
                              void* d_out, int out_size, void* d_ws, size_t ws_size,
                              hipStream_t stream) {
  const float* x    = (const float*)d_in[0];
  const float* w_ih = (const float*)d_in[1];
  const float* w_hh = (const float*)d_in[2];
  const float* b_ih = (const float*)d_in[3];
  const float* b_hh = (const float*)d_in[4];
  const float* w_fc = (const float*)d_in[5];
  const float* b_fc = (const float*)d_in[6];
  float* out = (float*)d_out;

  const int B = out_size;          // 16384
  const int T = in_sizes[0] / B;   // 2048

  dim3 grid(B / MB), block(TPB);
  hipLaunchKernelGGL(lstm_mfma4, grid, block, 0, stream,
                     x, w_ih, w_hh, b_ih, b_hh, w_fc, b_fc, out, T);
}

// Round 5
// 2283.420 us; speedup vs baseline: 17.2791x; 1.0137x over previous
//
#include <hip/hip_runtime.h>
#include <cstdint>

typedef __attribute__((ext_vector_type(8))) short short8;
typedef __attribute__((ext_vector_type(4))) float f32x4;
typedef __attribute__((ext_vector_type(2))) float f32x2;

#define TPB  256
#define MB   16      // batch rows per block
#define HS   50      // hidden size
#define HSTR 72      // h row stride in halves (144B, 16B-aligned)
#define XSTR 68      // x row stride in u32 (272B, 16B-aligned)
#define L2E  1.4426950408889634f
#define L2E2 2.8853900817779268f

__device__ __forceinline__ float ex2(float x) {
#if __has_builtin(__builtin_amdgcn_exp2f)
  return __builtin_amdgcn_exp2f(x);
#else
  float r; asm("v_exp_f32 %0, %1" : "=v"(r) : "v"(x)); return r;
#endif
}
__device__ __forceinline__ float rcp_(float x) {
#if __has_builtin(__builtin_amdgcn_rcpf)
  return __builtin_amdgcn_rcpf(x);
#else
  float r; asm("v_rcp_f32 %0, %1" : "=v"(r) : "v"(x)); return r;
#endif
}
__device__ __forceinline__ unsigned short bf16_rne(float f) {
  unsigned r;
  asm("v_cvt_pk_bf16_f32 %0, %1, %2" : "=v"(r) : "v"(f), "v"(f));
  return (unsigned short)r;
}
__device__ __forceinline__ float bf16f(unsigned short h) {
  union { unsigned u; float f; } v; v.u = ((unsigned)h) << 16; return v.f;
}
// pack x value as (hi bf16 | lo bf16 << 16)
__device__ __forceinline__ unsigned packx(float f) {
  unsigned short hi = bf16_rne(f);
  unsigned short lo = bf16_rne(f - bf16f(hi));
  return (unsigned)hi | ((unsigned)lo << 16);
}
// column swizzle: XOR 8-col block index with (row>>2)&3 (consistent read/write)
__device__ __forceinline__ int swcol(int row, int col) {
  return (((col >> 3) ^ ((row >> 2) & 3)) << 3) | (col & 7);
}

// A (per step): 16 rows (batch) x 64 K-cols:
//   k 0..49 = h(t-1) bf16, k50 = xv_hi, k51 = xv_lo, k52 = xv_hi,
//   k53 = 1.0, k54 = 1.0, k55..63 = 0
// B rows prescaled by log2e (2*log2e for g). B frag1 k-slots:
//   k50,k51 = w_ih_hi, k52 = w_ih_lo, k53 = bias_hi, k54 = bias_lo
// MFMA per gate: Ah0*Bh0 + Ah0*Bl0 + Ah1*Bh1   (12 total)
__global__ __launch_bounds__(TPB, 4)
void lstm_mfma5(const float* __restrict__ x,
                const float* __restrict__ w_ih,
                const float* __restrict__ w_hh,
                const float* __restrict__ b_ih,
                const float* __restrict__ b_hh,
                const float* __restrict__ w_fc,
                const float* __restrict__ b_fc,
                float* __restrict__ out, int T)
{
  __shared__ __attribute__((aligned(16))) unsigned short hbuf[2][MB][HSTR];
  __shared__ __attribute__((aligned(16))) unsigned x_lds[2][MB][XSTR];

  // phase-stagger co-resident blocks (ids differ by 256 on one CU at 1024
  // blocks / 256 CU) so MFMA-phase and VALU-phase waves coexist on a SIMD
  switch ((blockIdx.x >> 8) & 3) {
    case 1: __builtin_amdgcn_s_sleep(3); break;   // ~192 cyc
    case 2: __builtin_amdgcn_s_sleep(6); break;   // ~384 cyc
    case 3: __builtin_amdgcn_s_sleep(9); break;   // ~576 cyc
    default: break;
  }

  const int tid  = threadIdx.x;
  const int wid  = tid >> 6;
  const int lane = tid & 63;
  const int l15  = lane & 15;
  const int lhi  = lane >> 4;      // 0..3
  const int b0   = blockIdx.x * MB;
  const int j    = wid * 16 + l15; // gate column this lane owns
  const bool jval = (j < HS);
  const bool inj  = (lhi == 2);    // lanes whose Ah1 carries k=48..55

  // ---- build static B-fragments ----
  short8 Bh[4][2], Bl0[4];
  #pragma unroll
  for (int s = 0; s < 4; ++s) {
    const float sc = (s == 2) ? L2E2 : L2E;
    float wsc = 0.f, bsc = 0.f;
    if (jval) {
      int row = s * HS + j;
      wsc = w_ih[row] * sc;
      bsc = (b_ih[row] + b_hh[row]) * sc;
    }
    const unsigned short wh = bf16_rne(wsc);
    const unsigned short wl = bf16_rne(wsc - bf16f(wh));
    const unsigned short bh = bf16_rne(bsc);
    const unsigned short bl = bf16_rne(bsc - bf16f(bh));
    #pragma unroll
    for (int i = 0; i < 8; ++i) {           // frag 0: k = 0..31, hi+lo
      int k = lhi * 8 + i;
      float val = jval ? w_hh[(s * HS + j) * HS + k] * sc : 0.f;
      unsigned short hi = bf16_rne(val);
      Bh[s][0][i] = (short)hi;
      Bl0[s][i]   = (short)bf16_rne(val - bf16f(hi));
    }
    #pragma unroll
    for (int i = 0; i < 8; ++i) {           // frag 1: k = 32..63, hi only
      int k = 32 + lhi * 8 + i;
      unsigned short hv = 0;
      if (jval) {
        if (k < HS)                hv = bf16_rne(w_hh[(s * HS + j) * HS + k] * sc);
        else if (k == 50 || k == 51) hv = wh;
        else if (k == 52)          hv = wl;
        else if (k == 53)          hv = bh;
        else if (k == 54)          hv = bl;
      }
      Bh[s][1][i] = (short)hv;
    }
  }

  // ---- init LDS ----
  for (int idx = tid; idx < 2 * MB * HSTR; idx += TPB)
    (&hbuf[0][0][0])[idx] = 0;
  {
    // stage x chunk 0 (coalesced float4 -> packed hi/lo u32)
    int bb = tid >> 4, tt = (tid & 15) * 4;
    const f32x4 v = *(const f32x4*)(x + (size_t)(b0 + bb) * T + tt);
    uint4 up;
    up.x = packx(v[0]); up.y = packx(v[1]); up.z = packx(v[2]); up.w = packx(v[3]);
    *(uint4*)&x_lds[0][bb][tt] = up;
  }
  __syncthreads();

  // loop-invariant LDS offsets (halves)
  const int keyr  = (l15 >> 2) & 3;
  const int offA0 = l15 * HSTR + ((lhi ^ keyr) << 3);
  const int offA1 = l15 * HSTR + (((lhi + 4) ^ keyr) << 3);
  const int offW0 = (lhi * 4) * HSTR + swcol(lhi * 4, j);

  // cell state carried SCALED: c~ = 2*log2e * c  (q = ex2(c~) directly)
  f32x2 cA = {0.f, 0.f}, cB = {0.f, 0.f};
  f32x4 xf = {0.f, 0.f, 0.f, 0.f};

  const unsigned short* hr = &hbuf[0][0][0];
  unsigned short*       hw = &hbuf[1][0][0];
  const int nch = T >> 6;

  for (int t = 0; t < T; ++t) {
    // T14-split x staging: issue global load early, LDS-write late
    if ((t & 63) == 16) {
      int c1 = (t >> 6) + 1;
      if (c1 < nch)
        xf = *(const f32x4*)(x + (size_t)(b0 + (tid >> 4)) * T + c1 * 64 + (tid & 15) * 4);
    }
    if ((t & 63) == 44) {
      int c1 = (t >> 6) + 1;
      if (c1 < nch) {
        uint4 up;
        up.x = packx(xf[0]); up.y = packx(xf[1]);
        up.z = packx(xf[2]); up.w = packx(xf[3]);
        *(uint4*)&x_lds[c1 & 1][tid >> 4][(tid & 15) * 4] = up;
      }
    }

    // A-frags + xv/bias register injection (lanes lhi==2 only)
    const unsigned xp = x_lds[(t >> 6) & 1][l15][t & 63];
    const short8 A0 = *(const short8*)(hr + offA0);
    union { short8 s8; unsigned u[4]; } a1;
    a1.s8 = *(const short8*)(hr + offA1);
    a1.u[1] = inj ? xp : a1.u[1];
    a1.u[2] = inj ? ((xp & 0xFFFFu) | 0x3F800000u) : a1.u[2];
    a1.u[3] = inj ? 0x00003F80u : a1.u[3];

    __builtin_amdgcn_s_setprio(1);
    f32x4 acc[4];
    #pragma unroll
    for (int s = 0; s < 4; ++s) {
      acc[s] = __builtin_amdgcn_mfma_f32_16x16x32_bf16(A0, Bh[s][0],
                   (f32x4){0.f, 0.f, 0.f, 0.f}, 0, 0, 0);
      acc[s] = __builtin_amdgcn_mfma_f32_16x16x32_bf16(A0, Bl0[s], acc[s], 0, 0, 0);
      acc[s] = __builtin_amdgcn_mfma_f32_16x16x32_bf16(a1.s8, Bh[s][1], acc[s], 0, 0, 0);
    }
    __builtin_amdgcn_s_setprio(0);

    // elementwise: u=2^-ai v=2^2ag w=2^-af z=2^-ao
    //   c~' = (c~*t1 + (v*L2E2 - L2E2)*wp) / (t1*wp)   [1 rcp, 1 fma folds L2E2]
    //   q = 2^c~' ; h = (q-1)/((1+z)(1+q))             [1 rcp]
    f32x2 h2[2];
    #pragma unroll
    for (int P = 0; P < 2; ++P) {
      f32x2& c2 = P ? cB : cA;
      f32x2 u, v, w, z, q, rD, r3, vm1;
      u[0] = ex2(-acc[0][2*P]);  u[1] = ex2(-acc[0][2*P+1]);
      v[0] = ex2( acc[2][2*P]);  v[1] = ex2( acc[2][2*P+1]);
      w[0] = ex2(-acc[1][2*P]);  w[1] = ex2(-acc[1][2*P+1]);
      z[0] = ex2(-acc[3][2*P]);  z[1] = ex2(-acc[3][2*P+1]);
      f32x2 t1 = (u + 1.f) * (v + 1.f);
      f32x2 wp = w + 1.f;
      f32x2 D  = t1 * wp;
      rD[0] = rcp_(D[0]); rD[1] = rcp_(D[1]);
      vm1[0] = fmaf(v[0], L2E2, -L2E2);
      vm1[1] = fmaf(v[1], L2E2, -L2E2);
      f32x2 num = c2 * t1 + vm1 * wp;
      f32x2 cn = num * rD;
      cn[0] = fminf(fmaxf(cn[0], -86.f), 86.f);
      cn[1] = fminf(fmaxf(cn[1], -86.f), 86.f);
      c2 = cn;
      q[0] = ex2(cn[0]); q[1] = ex2(cn[1]);
      f32x2 t3 = (z + 1.f) * (q + 1.f);
      r3[0] = rcp_(t3[0]); r3[1] = rcp_(t3[1]);
      h2[P] = (q - 1.f) * r3;
    }

    if (jval) {
      hw[offW0           ] = bf16_rne(h2[0][0]);
      hw[offW0 +     HSTR] = bf16_rne(h2[0][1]);
      hw[offW0 + 2 * HSTR] = bf16_rne(h2[1][0]);
      hw[offW0 + 3 * HSTR] = bf16_rne(h2[1][1]);
    }

    __syncthreads();   // h(t) visible; everyone done reading hr

    unsigned short* tmp = (unsigned short*)hr; hr = hw; hw = tmp;
  }

  // fc head on final h
  if (tid < MB) {
    const unsigned short* hfin = hr + tid * HSTR;
    float s = 0.f;
    for (int jj = 0; jj < HS; ++jj)
      s = fmaf(bf16f(hfin[swcol(tid, jj)]), w_fc[jj], s);
    out[b0 + tid] = s + b_fc[0];
  }
}

extern "C" void kernel_launch(void* const* d_in, const int* in_sizes, int n_in,
                              void* d_out, int out_size, void* d_ws, size_t ws_size,
                              hipStream_t stream) {
  const float* x    = (const float*)d_in[0];
  const float* w_ih = (const float*)d_in[1];
  const float* w_hh = (const float*)d_in[2];
  const float* b_ih = (const float*)d_in[3];
  const float* b_hh = (const float*)d_in[4];
  const float* w_fc = (const float*)d_in[5];
  const float* b_fc = (const float*)d_in[6];
  float* out = (float*)d_out;

  const int B = out_size;          // 16384
  const int T = in_sizes[0] / B;   // 2048

  dim3 grid(B / MB), block(TPB);
  hipLaunchKernelGGL(lstm_mfma5, grid, block, 0, stream,
                     x, w_ih, w_hh, b_ih, b_hh, w_fc, b_fc, out, T);
}

// Round 7
// 1963.354 us; speedup vs baseline: 20.0959x; 1.1630x over previous
//
#include <hip/hip_runtime.h>
#include <cstdint>

typedef __attribute__((ext_vector_type(8))) short short8;
typedef __attribute__((ext_vector_type(4))) float f32x4;
typedef __attribute__((ext_vector_type(2))) float f32x2;

#define TPB  256
#define MB   16      // batch rows per block
#define HS   50      // hidden size
#define HSTR 72      // h row stride in halves (144B, 16B-aligned)
#define XSTR 68      // x row stride in u32 (272B, 16B-aligned)
#define L2E  1.4426950408889634f
#define L2E2 2.8853900817779268f

__device__ __forceinline__ float ex2(float x) {
#if __has_builtin(__builtin_amdgcn_exp2f)
  return __builtin_amdgcn_exp2f(x);
#else
  float r; asm("v_exp_f32 %0, %1" : "=v"(r) : "v"(x)); return r;
#endif
}
__device__ __forceinline__ float rcp_(float x) {
#if __has_builtin(__builtin_amdgcn_rcpf)
  return __builtin_amdgcn_rcpf(x);
#else
  float r; asm("v_rcp_f32 %0, %1" : "=v"(r) : "v"(x)); return r;
#endif
}
__device__ __forceinline__ unsigned short bf16_rne(float f) {
  unsigned r;
  asm("v_cvt_pk_bf16_f32 %0, %1, %2" : "=v"(r) : "v"(f), "v"(f));
  return (unsigned short)r;
}
__device__ __forceinline__ unsigned cvtpk2(float a, float b) {
  unsigned r;
  asm("v_cvt_pk_bf16_f32 %0, %1, %2" : "=v"(r) : "v"(a), "v"(b));
  return r;   // lo = a, hi = b
}
__device__ __forceinline__ float bf16f(unsigned short h) {
  union { unsigned u; float f; } v; v.u = ((unsigned)h) << 16; return v.f;
}
__device__ __forceinline__ unsigned packx(float f) {
  unsigned short hi = bf16_rne(f);
  unsigned short lo = bf16_rne(f - bf16f(hi));
  return (unsigned)hi | ((unsigned)lo << 16);
}
// column swizzle (identical helper on every read and write)
__device__ __forceinline__ int swcol(int row, int col) {
  return (((col >> 3) ^ ((row >> 2) & 3)) << 3) | (col & 7);
}

// Transposed GEMM per step: gates^T[256 n][16 b] = W[256 n][64 k] * hT[64 k][16 b]
//   A-operand = W fragments (static, registers); B-operand = h^T from LDS.
//   k 0..49 = h(t-1); reg-injected on B frag1: k50=xv_hi k51=xv_lo k52=xv_hi
//   k53=1 k54=1 (paired with W frag1 slots: w_ih_hi, w_ih_hi, w_ih_lo,
//   bias_hi, bias_lo). W rows prescaled by log2e (2*log2e for g-gate).
//   C: row j = wid*16 + lhi*4 + r, col b = l15 -> lane owns 4 consecutive j
//   for one batch row: single packed ds_write_b64 h-write, unconditional
//   (padding cols 50..55 are reg-injected on read, 56..63 zero-weighted).
__global__ __launch_bounds__(TPB, 4)
void lstm_mfma7(const float* __restrict__ x,
                const float* __restrict__ w_ih,
                const float* __restrict__ w_hh,
                const float* __restrict__ b_ih,
                const float* __restrict__ b_hh,
                const float* __restrict__ w_fc,
                const float* __restrict__ b_fc,
                float* __restrict__ out, int T)
{
  __shared__ __attribute__((aligned(16))) unsigned short hbuf[2][MB][HSTR];
  __shared__ __attribute__((aligned(16))) unsigned x_lds[2][MB][XSTR];

  const int tid  = threadIdx.x;
  const int wid  = tid >> 6;
  const int lane = tid & 63;
  const int l15  = lane & 15;
  const int lhi  = lane >> 4;      // 0..3
  const int b0   = blockIdx.x * MB;
  const int j    = wid * 16 + l15; // W row this lane LOADS (A-frag mapping)
  const bool jval = (j < HS);
  const bool inj  = (lhi == 2);    // B-frag1 lanes carrying k=48..55

  // ---- build static W-fragments (A-operand), hi-only + xv/bias slots ----
  short8 Wh[4][2];
  #pragma unroll
  for (int s = 0; s < 4; ++s) {
    const float sc = (s == 2) ? L2E2 : L2E;
    float wsc = 0.f, bsc = 0.f;
    if (jval) {
      int row = s * HS + j;
      wsc = w_ih[row] * sc;
      bsc = (b_ih[row] + b_hh[row]) * sc;
    }
    const unsigned short wh = bf16_rne(wsc);
    const unsigned short wl = bf16_rne(wsc - bf16f(wh));
    const unsigned short bh = bf16_rne(bsc);
    const unsigned short bl = bf16_rne(bsc - bf16f(bh));
    #pragma unroll
    for (int i = 0; i < 8; ++i) {           // frag 0: k = 0..31
      int k = lhi * 8 + i;
      Wh[s][0][i] = (short)(jval ? bf16_rne(w_hh[(s * HS + j) * HS + k] * sc) : 0);
    }
    #pragma unroll
    for (int i = 0; i < 8; ++i) {           // frag 1: k = 32..63
      int k = 32 + lhi * 8 + i;
      unsigned short hv = 0;
      if (jval) {
        if (k < HS)                  hv = bf16_rne(w_hh[(s * HS + j) * HS + k] * sc);
        else if (k == 50 || k == 51) hv = wh;
        else if (k == 52)            hv = wl;
        else if (k == 53)            hv = bh;
        else if (k == 54)            hv = bl;
      }
      Wh[s][1][i] = (short)hv;
    }
  }

  // ---- init LDS ----
  for (int idx = tid; idx < 2 * MB * HSTR; idx += TPB)
    (&hbuf[0][0][0])[idx] = 0;
  {
    int bb = tid >> 4, tt = (tid & 15) * 4;
    const f32x4 v = *(const f32x4*)(x + (size_t)(b0 + bb) * T + tt);
    uint4 up;
    up.x = packx(v[0]); up.y = packx(v[1]); up.z = packx(v[2]); up.w = packx(v[3]);
    *(uint4*)&x_lds[0][bb][tt] = up;
  }
  __syncthreads();

  // loop-invariant LDS offsets (halves)
  const int keyr  = (l15 >> 2) & 3;
  const int offA0 = l15 * HSTR + ((lhi ^ keyr) << 3);
  const int offA1 = l15 * HSTR + (((lhi + 4) ^ keyr) << 3);
  // packed h-write: row b=l15, 4 halves at cols j_base..j_base+3,
  // j_base = wid*16 + lhi*4  (swizzle-consistent with swcol)
  const int offW  = l15 * HSTR + ((((wid * 2 + (lhi >> 1)) ^ keyr) << 3)) + (lhi & 1) * 4;

  // cell state carried scaled: c~ = 2*log2e*c ; rows r=0,1 in cA, r=2,3 in cB
  f32x2 cA = {0.f, 0.f}, cB = {0.f, 0.f};
  f32x4 xf = {0.f, 0.f, 0.f, 0.f};
  const int nch = T >> 6;

  auto STEP = [&](const unsigned short* hr, unsigned short* hw, int t) {
    // T14-split x staging: issue global load early, LDS-write late
    if ((t & 63) == 16) {
      int c1 = (t >> 6) + 1;
      if (c1 < nch)
        xf = *(const f32x4*)(x + (size_t)(b0 + (tid >> 4)) * T + c1 * 64 + (tid & 15) * 4);
    }
    if ((t & 63) == 44) {
      int c1 = (t >> 6) + 1;
      if (c1 < nch) {
        uint4 up;
        up.x = packx(xf[0]); up.y = packx(xf[1]);
        up.z = packx(xf[2]); up.w = packx(xf[3]);
        *(uint4*)&x_lds[c1 & 1][tid >> 4][(tid & 15) * 4] = up;
      }
    }

    // B-operand (h^T) frags + xv/bias register injection (lanes lhi==2)
    const unsigned xp = x_lds[(t >> 6) & 1][l15][t & 63];
    const short8 B0 = *(const short8*)(hr + offA0);
    union { short8 s8; unsigned u[4]; } b1;
    b1.s8 = *(const short8*)(hr + offA1);
    b1.u[1] = inj ? xp : b1.u[1];
    b1.u[2] = inj ? ((xp & 0xFFFFu) | 0x3F800000u) : b1.u[2];
    b1.u[3] = inj ? 0x00003F80u : b1.u[3];

    __builtin_amdgcn_s_setprio(1);
    f32x4 acc[4];
    #pragma unroll
    for (int s = 0; s < 4; ++s) {
      acc[s] = __builtin_amdgcn_mfma_f32_16x16x32_bf16(Wh[s][0], B0,
                   (f32x4){0.f, 0.f, 0.f, 0.f}, 0, 0, 0);
      acc[s] = __builtin_amdgcn_mfma_f32_16x16x32_bf16(Wh[s][1], b1.s8, acc[s], 0, 0, 0);
    }
    __builtin_amdgcn_s_setprio(0);

    // elementwise (round-5 scalar form, known-good):
    //   u=2^-ai v=2^2ag w=2^-af z=2^-ao
    //   c~' = (c~*t1 + (v*2log2e - 2log2e)*wp) * rcp(t1*wp)   (clamp ±86)
    //   q = 2^c~' ; h = (q-1) * rcp((1+z)(1+q))
    f32x2 h2A, h2B;
    {
      f32x2 u, v, w, z, q, rD, r3, vm1;
      u[0] = ex2(-acc[0][0]); u[1] = ex2(-acc[0][1]);
      v[0] = ex2( acc[2][0]); v[1] = ex2( acc[2][1]);
      w[0] = ex2(-acc[1][0]); w[1] = ex2(-acc[1][1]);
      z[0] = ex2(-acc[3][0]); z[1] = ex2(-acc[3][1]);
      f32x2 t1 = (u + 1.f) * (v + 1.f);
      f32x2 wp = w + 1.f;
      f32x2 D  = t1 * wp;
      rD[0] = rcp_(D[0]); rD[1] = rcp_(D[1]);
      vm1[0] = fmaf(v[0], L2E2, -L2E2);
      vm1[1] = fmaf(v[1], L2E2, -L2E2);
      f32x2 num = cA * t1 + vm1 * wp;
      f32x2 cn = num * rD;
      cn[0] = fminf(fmaxf(cn[0], -86.f), 86.f);
      cn[1] = fminf(fmaxf(cn[1], -86.f), 86.f);
      cA = cn;
      q[0] = ex2(cn[0]); q[1] = ex2(cn[1]);
      f32x2 t3 = (z + 1.f) * (q + 1.f);
      r3[0] = rcp_(t3[0]); r3[1] = rcp_(t3[1]);
      h2A = (q - 1.f) * r3;
    }
    {
      f32x2 u, v, w, z, q, rD, r3, vm1;
      u[0] = ex2(-acc[0][2]); u[1] = ex2(-acc[0][3]);
      v[0] = ex2( acc[2][2]); v[1] = ex2( acc[2][3]);
      w[0] = ex2(-acc[1][2]); w[1] = ex2(-acc[1][3]);
      z[0] = ex2(-acc[3][2]); z[1] = ex2(-acc[3][3]);
      f32x2 t1 = (u + 1.f) * (v + 1.f);
      f32x2 wp = w + 1.f;
      f32x2 D  = t1 * wp;
      rD[0] = rcp_(D[0]); rD[1] = rcp_(D[1]);
      vm1[0] = fmaf(v[0], L2E2, -L2E2);
      vm1[1] = fmaf(v[1], L2E2, -L2E2);
      f32x2 num = cB * t1 + vm1 * wp;
      f32x2 cn = num * rD;
      cn[0] = fminf(fmaxf(cn[0], -86.f), 86.f);
      cn[1] = fminf(fmaxf(cn[1], -86.f), 86.f);
      cB = cn;
      q[0] = ex2(cn[0]); q[1] = ex2(cn[1]);
      f32x2 t3 = (z + 1.f) * (q + 1.f);
      r3[0] = rcp_(t3[0]); r3[1] = rcp_(t3[1]);
      h2B = (q - 1.f) * r3;
    }

    // packed h-write: 4 consecutive j at row b=l15, unconditional
    uint2 hwv;
    hwv.x = cvtpk2(h2A[0], h2A[1]);
    hwv.y = cvtpk2(h2B[0], h2B[1]);
    *(uint2*)(hw + offW) = hwv;

    __syncthreads();
  };

  unsigned short* hb0 = &hbuf[0][0][0];
  unsigned short* hb1 = &hbuf[1][0][0];
  for (int tb = 0; tb < T; tb += 2) {   // T even; static buffer parity
    STEP(hb0, hb1, tb);
    STEP(hb1, hb0, tb + 1);
  }

  // fc head on final h (T even -> final h in hbuf[0])
  if (tid < MB) {
    const unsigned short* hfin = hb0 + tid * HSTR;
    float s = 0.f;
    for (int jj = 0; jj < HS; ++jj)
      s = fmaf(bf16f(hfin[swcol(tid, jj)]), w_fc[jj], s);
    out[b0 + tid] = s + b_fc[0];
  }
}

extern "C" void kernel_launch(void* const* d_in, const int* in_sizes, int n_in,
                              void* d_out, int out_size, void* d_ws, size_t ws_size,
                              hipStream_t stream) {
  const float* x    = (const float*)d_in[0];
  const float* w_ih = (const float*)d_in[1];
  const float* w_hh = (const float*)d_in[2];
  const float* b_ih = (const float*)d_in[3];
  const float* b_hh = (const float*)d_in[4];
  const float* w_fc = (const float*)d_in[5];
  const float* b_fc = (const float*)d_in[6];
  float* out = (float*)d_out;

  const int B = out_size;          // 16384
  const int T = in_sizes[0] / B;   // 2048

  dim3 grid(B / MB), block(TPB);
  hipLaunchKernelGGL(lstm_mfma7, grid, block, 0, stream,
                     x, w_ih, w_hh, b_ih, b_hh, w_fc, b_fc, out, T);
}

// Round 10
// 1929.818 us; speedup vs baseline: 20.4451x; 1.0174x over previous
//
#include <hip/hip_runtime.h>
#include <cstdint>

typedef __attribute__((ext_vector_type(8))) short short8;
typedef __attribute__((ext_vector_type(4))) float f32x4;
typedef __attribute__((ext_vector_type(2))) float f32x2;

#define TPB  256
#define MB   16      // batch rows per block
#define HS   50      // hidden size
#define HSTR 72      // h row stride in halves (144B, 16B-aligned)
#define XSTR 68      // x row stride in u32 (272B, 16B-aligned)
#define L2E  1.4426950408889634f
#define L2E2 2.8853900817779268f

__device__ __forceinline__ float ex2(float x) {
#if __has_builtin(__builtin_amdgcn_exp2f)
  return __builtin_amdgcn_exp2f(x);
#else
  float r; asm("v_exp_f32 %0, %1" : "=v"(r) : "v"(x)); return r;
#endif
}
__device__ __forceinline__ float rcp_(float x) {
#if __has_builtin(__builtin_amdgcn_rcpf)
  return __builtin_amdgcn_rcpf(x);
#else
  float r; asm("v_rcp_f32 %0, %1" : "=v"(r) : "v"(x)); return r;
#endif
}
__device__ __forceinline__ unsigned short bf16_rne(float f) {
  unsigned r;
  asm("v_cvt_pk_bf16_f32 %0, %1, %2" : "=v"(r) : "v"(f), "v"(f));
  return (unsigned short)r;
}
__device__ __forceinline__ unsigned cvtpk2(float a, float b) {
  unsigned r;
  asm("v_cvt_pk_bf16_f32 %0, %1, %2" : "=v"(r) : "v"(a), "v"(b));
  return r;   // lo = a, hi = b
}
__device__ __forceinline__ float bf16f(unsigned short h) {
  union { unsigned u; float f; } v; v.u = ((unsigned)h) << 16; return v.f;
}
__device__ __forceinline__ unsigned packx(float f) {
  unsigned short hi = bf16_rne(f);
  unsigned short lo = bf16_rne(f - bf16f(hi));
  return (unsigned)hi | ((unsigned)lo << 16);
}
// column swizzle (identical helper on every read and write)
__device__ __forceinline__ int swcol(int row, int col) {
  return (((col >> 3) ^ ((row >> 2) & 3)) << 3) | (col & 7);
}

// Transposed GEMM per step: gates^T[256 n][16 b] = W[256 n][64 k] * hT[64 k][16 b]
//   A-operand = W fragments (static, registers); B-operand = h^T from LDS.
//   k 0..49 = h(t-1); reg-injected on B frag1: k50=xv_hi k51=xv_lo k52=xv_hi
//   k53=1 k54=1 (paired with W frag1 slots: w_ih_hi, w_ih_hi, w_ih_lo,
//   bias_hi, bias_lo). W rows prescaled by log2e (2*log2e for g-gate).
//   Gate-chunk ROTATION: wave wid owns j-chunk g = (wid + rho)&3,
//   rho = (blockIdx>>8)&3 -> co-resident blocks place the light chunk (g==3,
//   87.5% padding) on different SIMDs -> balanced issue load.
//   Light wave skips its all-pad r=2,3 elementwise half.
__global__ __launch_bounds__(TPB, 4)
void lstm_mfma10(const float* __restrict__ x,
                 const float* __restrict__ w_ih,
                 const float* __restrict__ w_hh,
                 const float* __restrict__ b_ih,
                 const float* __restrict__ b_hh,
                 const float* __restrict__ w_fc,
                 const float* __restrict__ b_fc,
                 float* __restrict__ out, int T)
{
  __shared__ __attribute__((aligned(16))) unsigned short hbuf[2][MB][HSTR];
  __shared__ __attribute__((aligned(16))) unsigned x_lds[2][MB][XSTR];

  const int tid  = threadIdx.x;
  const int wid  = tid >> 6;
  const int lane = tid & 63;
  const int l15  = lane & 15;
  const int lhi  = lane >> 4;      // 0..3
  const int b0   = blockIdx.x * MB;
  const int rho  = (blockIdx.x >> 8) & 3;
  const int g    = (wid + rho) & 3;   // j-chunk this wave owns
  const int j    = g * 16 + l15;      // W row this lane loads
  const bool jval  = (j < HS);
  const bool light = (g == 3);        // j=48..63: r=2,3 all-pad
  const bool inj   = (lhi == 2);      // B-frag1 lanes carrying k=48..55

  // ---- build static W-fragments (A-operand), hi-only + xv/bias slots ----
  short8 Wh[4][2];
  #pragma unroll
  for (int s = 0; s < 4; ++s) {
    const float sc = (s == 2) ? L2E2 : L2E;
    float wsc = 0.f, bsc = 0.f;
    if (jval) {
      int row = s * HS + j;
      wsc = w_ih[row] * sc;
      bsc = (b_ih[row] + b_hh[row]) * sc;
    }
    const unsigned short wh = bf16_rne(wsc);
    const unsigned short wl = bf16_rne(wsc - bf16f(wh));
    const unsigned short bh = bf16_rne(bsc);
    const unsigned short bl = bf16_rne(bsc - bf16f(bh));
    #pragma unroll
    for (int i = 0; i < 8; ++i) {           // frag 0: k = 0..31
      int k = lhi * 8 + i;
      Wh[s][0][i] = (short)(jval ? bf16_rne(w_hh[(s * HS + j) * HS + k] * sc) : 0);
    }
    #pragma unroll
    for (int i = 0; i < 8; ++i) {           // frag 1: k = 32..63
      int k = 32 + lhi * 8 + i;
      unsigned short hv = 0;
      if (jval) {
        if (k < HS)                  hv = bf16_rne(w_hh[(s * HS + j) * HS + k] * sc);
        else if (k == 50 || k == 51) hv = wh;
        else if (k == 52)            hv = wl;
        else if (k == 53)            hv = bh;
        else if (k == 54)            hv = bl;
      }
      Wh[s][1][i] = (short)hv;
    }
  }

  // ---- init LDS ----
  for (int idx = tid; idx < 2 * MB * HSTR; idx += TPB)
    (&hbuf[0][0][0])[idx] = 0;
  {
    int bb = tid >> 4, tt = (tid & 15) * 4;
    const f32x4 v = *(const f32x4*)(x + (size_t)(b0 + bb) * T + tt);
    uint4 up;
    up.x = packx(v[0]); up.y = packx(v[1]); up.z = packx(v[2]); up.w = packx(v[3]);
    *(uint4*)&x_lds[0][bb][tt] = up;
  }
  __syncthreads();

  // loop-invariant LDS offsets (halves)
  const int keyr  = (l15 >> 2) & 3;
  const int offA0 = l15 * HSTR + ((lhi ^ keyr) << 3);
  const int offA1 = l15 * HSTR + (((lhi + 4) ^ keyr) << 3);
  // packed h-write: row b=l15, 4 halves at cols j_base..j_base+3,
  // j_base = g*16 + lhi*4 (swizzle-consistent with swcol)
  const int offW  = l15 * HSTR + ((((g * 2 + (lhi >> 1)) ^ keyr) << 3)) + (lhi & 1) * 4;

  // cell state carried scaled: c~ = 2*log2e*c ; rows r=0,1 in cA, r=2,3 in cB
  f32x2 cA = {0.f, 0.f}, cB = {0.f, 0.f};
  f32x4 xf = {0.f, 0.f, 0.f, 0.f};
  const int nch = T >> 6;   // T assumed multiple of 64 (T=2048)

  // elementwise core (identical arithmetic to round-7 known-good):
  //   u=2^-ai v=2^2ag w=2^-af z=2^-ao
  //   c~' = (c~*t1 + (v*2log2e - 2log2e)*wp) * rcp(t1*wp)   (clamp ±86)
  //   q = 2^c~' ; h = (q-1) * rcp((1+z)(1+q))
  auto ELEM = [&](f32x2 ai, f32x2 af, f32x2 ag, f32x2 ao, f32x2& c2) -> f32x2 {
    f32x2 u, v, w, z, q, rD, r3, vm1;
    u[0] = ex2(-ai[0]); u[1] = ex2(-ai[1]);
    v[0] = ex2( ag[0]); v[1] = ex2( ag[1]);
    w[0] = ex2(-af[0]); w[1] = ex2(-af[1]);
    z[0] = ex2(-ao[0]); z[1] = ex2(-ao[1]);
    f32x2 t1 = (u + 1.f) * (v + 1.f);
    f32x2 wp = w + 1.f;
    f32x2 D  = t1 * wp;
    rD[0] = rcp_(D[0]); rD[1] = rcp_(D[1]);
    vm1[0] = fmaf(v[0], L2E2, -L2E2);
    vm1[1] = fmaf(v[1], L2E2, -L2E2);
    f32x2 num = c2 * t1 + vm1 * wp;
    f32x2 cn = num * rD;
    cn[0] = fminf(fmaxf(cn[0], -86.f), 86.f);
    cn[1] = fminf(fmaxf(cn[1], -86.f), 86.f);
    c2 = cn;
    q[0] = ex2(cn[0]); q[1] = ex2(cn[1]);
    f32x2 t3 = (z + 1.f) * (q + 1.f);
    r3[0] = rcp_(t3[0]); r3[1] = rcp_(t3[1]);
    return (q - 1.f) * r3;
  };

  auto STEP = [&](const unsigned short* hr, unsigned short* hw,
                  const unsigned* xrow, int slot) {
    // B-operand (h^T) frags + xv/bias register injection (lanes lhi==2)
    const unsigned xp = xrow[slot];
    const short8 B0 = *(const short8*)(hr + offA0);
    union { short8 s8; unsigned u[4]; } b1;
    b1.s8 = *(const short8*)(hr + offA1);
    b1.u[1] = inj ? xp : b1.u[1];
    b1.u[2] = inj ? ((xp & 0xFFFFu) | 0x3F800000u) : b1.u[2];
    b1.u[3] = inj ? 0x00003F80u : b1.u[3];

    __builtin_amdgcn_s_setprio(1);
    f32x4 acc[4];
    #pragma unroll
    for (int s = 0; s < 4; ++s) {
      acc[s] = __builtin_amdgcn_mfma_f32_16x16x32_bf16(Wh[s][0], B0,
                   (f32x4){0.f, 0.f, 0.f, 0.f}, 0, 0, 0);
      acc[s] = __builtin_amdgcn_mfma_f32_16x16x32_bf16(Wh[s][1], b1.s8, acc[s], 0, 0, 0);
    }
    __builtin_amdgcn_s_setprio(0);

    f32x2 h2A = ELEM((f32x2){acc[0][0], acc[0][1]}, (f32x2){acc[1][0], acc[1][1]},
                     (f32x2){acc[2][0], acc[2][1]}, (f32x2){acc[3][0], acc[3][1]}, cA);
    unsigned hx = cvtpk2(h2A[0], h2A[1]);
    if (!light) {
      f32x2 h2B = ELEM((f32x2){acc[0][2], acc[0][3]}, (f32x2){acc[1][2], acc[1][3]},
                       (f32x2){acc[2][2], acc[2][3]}, (f32x2){acc[3][2], acc[3][3]}, cB);
      uint2 hwv;
      hwv.x = hx;
      hwv.y = cvtpk2(h2B[0], h2B[1]);
      *(uint2*)(hw + offW) = hwv;      // 4 consecutive j at row b=l15
    } else {
      // light wave: r=2,3 are all-pad (j>=50); write only j_base,j_base+1.
      // Skipped cols stay zero from init and are injection/zero-weight cols.
      *(unsigned*)(hw + offW) = hx;
    }

    __syncthreads();
  };

  unsigned short* hb0 = &hbuf[0][0][0];
  unsigned short* hb1 = &hbuf[1][0][0];

  for (int ch = 0; ch < nch; ++ch) {
    const int par = ch & 1;
    const unsigned* xrow = &x_lds[par][l15][0];
    int slot = 0;
    #pragma unroll 1
    for (int i = 0; i < 8; ++i) {          // slots 0..15
      STEP(hb0, hb1, xrow, slot); STEP(hb1, hb0, xrow, slot + 1); slot += 2;
    }
    if (ch + 1 < nch)                      // issue next-chunk global load (~slot 16)
      xf = *(const f32x4*)(x + (size_t)(b0 + (tid >> 4)) * T + (ch + 1) * 64 + (tid & 15) * 4);
    #pragma unroll 1
    for (int i = 0; i < 14; ++i) {         // slots 16..43
      STEP(hb0, hb1, xrow, slot); STEP(hb1, hb0, xrow, slot + 1); slot += 2;
    }
    if (ch + 1 < nch) {                    // write next-chunk x to LDS (~slot 44)
      uint4 up;
      up.x = packx(xf[0]); up.y = packx(xf[1]);
      up.z = packx(xf[2]); up.w = packx(xf[3]);
      *(uint4*)&x_lds[par ^ 1][tid >> 4][(tid & 15) * 4] = up;
    }
    #pragma unroll 1
    for (int i = 0; i < 10; ++i) {         // slots 44..63
      STEP(hb0, hb1, xrow, slot); STEP(hb1, hb0, xrow, slot + 1); slot += 2;
    }
  }

  // fc head on final h (T even -> final h in hbuf[0])
  if (tid < MB) {
    const unsigned short* hfin = hb0 + tid * HSTR;
    float s = 0.f;
    for (int jj = 0; jj < HS; ++jj)
      s = fmaf(bf16f(hfin[swcol(tid, jj)]), w_fc[jj], s);
    out[b0 + tid] = s + b_fc[0];
  }
}

extern "C" void kernel_launch(void* const* d_in, const int* in_sizes, int n_in,
                              void* d_out, int out_size, void* d_ws, size_t ws_size,
                              hipStream_t stream) {
  const float* x    = (const float*)d_in[0];
  const float* w_ih = (const float*)d_in[1];
  const float* w_hh = (const float*)d_in[2];
  const float* b_ih = (const float*)d_in[3];
  const float* b_hh = (const float*)d_in[4];
  const float* w_fc = (const float*)d_in[5];
  const float* b_fc = (const float*)d_in[6];
  float* out = (float*)d_out;

  const int B = out_size;          // 16384
  const int T = in_sizes[0] / B;   // 2048

  dim3 grid(B / MB), block(TPB);
  hipLaunchKernelGGL(lstm_mfma10, grid, block, 0, stream,
                     x, w_ih, w_hh, b_ih, b_hh, w_fc, b_fc, out, T);
}